// Round 3
// baseline (822.684 us; speedup 1.0000x reference)
//
#include <hip/hip_runtime.h>
#include <math.h>

// SparseNet: conv1(2x2,200->16,pad(0,1)) * mask -> maskedpool 3x3/3 ->
// conv2(5x5,16->32,VALID) * pooledmask -> maskedpool 3x3/1 -> linear(32,2) -> softmax
// B=1024, H=W=21, Cin=200.
//
// ws layout:
//   h2ord [1024*49*16] int   (3.2 MB)  pooled conv1 output, ordered-int max accum
//   m2    [1024*49] float               pooled mask (computed from mask directly)
//   wl    [451584] int                  compacted active-site worklist (b*441+p)
//   nact  [4] int
//   zp    [256] float                   zero page for inactive conv1 taps

#define NEGINF -1e30f

// Order-preserving float<->int map so masked max-pool can run as atomicMax.
__device__ __forceinline__ int f2o(float f) {
    int i = __float_as_int(f);
    return (i >= 0) ? i : (i ^ 0x7FFFFFFF);
}
__device__ __forceinline__ float o2f(int o) {
    return __int_as_float((o >= 0) ? o : (o ^ 0x7FFFFFFF));
}

// ---------------- K0: compact worklist + init h2ord + pooled mask ----------------
__global__ __launch_bounds__(256) void compact_kernel(
    const int* __restrict__ mask,   // [1024,21,21]
    int* __restrict__ wl,
    int* __restrict__ nact,
    int* __restrict__ h2ord,        // [1024,49,16] -> INT_MIN
    float* __restrict__ m2)         // [1024,49]
{
    __shared__ unsigned short loc[441];
    __shared__ unsigned char msk[441];
    __shared__ int cnt, base;
    const int b = blockIdx.x;
    const int t = threadIdx.x;
    if (t == 0) cnt = 0;
    __syncthreads();
    for (int p = t; p < 441; p += 256) {
        const int mv = mask[b * 441 + p];
        msk[p] = (unsigned char)(mv != 0);
        if (mv != 0) loc[atomicAdd(&cnt, 1)] = (unsigned short)p;
    }
    for (int v = t; v < 784; v += 256) h2ord[b * 784 + v] = 0x80000000; // INT_MIN
    __syncthreads();
    if (t == 0) base = atomicAdd(nact, cnt);
    __syncthreads();
    const int n = cnt, bs = base, off = b * 441;
    for (int k = t; k < n; k += 256) wl[bs + k] = off + loc[k];
    if (t < 49) {
        const int pr = t / 7, pc = t - pr * 7;
        int any = 0;
        #pragma unroll
        for (int r = 0; r < 3; ++r) {
            const unsigned char* mr = &msk[(pr * 3 + r) * 21 + pc * 3];
            any |= mr[0] | mr[1] | mr[2];
        }
        m2[b * 49 + t] = any ? 1.0f : 0.0f;
    }
}

// ---------------- K1: conv1 worklist-GEMM + fused pool1 via global atomicMax ----------------
// 2 sites/thread; per k4 iteration: 8 independent global loads (prefetched one
// iteration ahead) + 512 FMAs -> load latency hidden inside one iteration.
// Inactive taps read a zeroed LDS-hot page (branch-free, exact +0.0).
__global__ __launch_bounds__(256, 3) void conv1_kernel(
    const float* __restrict__ x,     // [1024,21,21,200]
    const int*   __restrict__ mask,  // [1024,21,21]
    const float* __restrict__ W1,    // [2,2,200,16]
    const int*   __restrict__ wl,
    const int*   __restrict__ nact,
    const float* __restrict__ zp,    // 200+ zero floats
    int* __restrict__ h2ord)         // [1024,49,16]
{
    __shared__ float w1s[4 * 200 * 16];   // 51.2 KB, layout [tap][k][oc]
    {
        const float4* __restrict__ wg = (const float4*)W1;
        float4* wd = (float4*)w1s;
        for (int v = threadIdx.x; v < 3200; v += 256) wd[v] = wg[v];
    }
    __syncthreads();

    const int n = *nact;
    if (n == 0) return;
    const int npairs = (n + 1) >> 1;
    const int gtid = blockIdx.x * 256 + threadIdx.x;
    const int gstride = gridDim.x * 256;

    for (int pr_ = gtid; pr_ < npairs; pr_ += gstride) {
        const int iA = wl[pr_ * 2];
        const int iB = wl[min(pr_ * 2 + 1, n - 1)];
        const int bA = iA / 441, pA = iA - bA * 441;
        const int bB = iB / 441, pB = iB - bB * 441;
        const int ia = pA / 21, ja = pA - ia * 21;
        const int ib = pB / 21, jb = pB - ib * 21;

        const float4* pa[4];
        const float4* pb[4];
        #pragma unroll
        for (int tap = 0; tap < 4; ++tap) {
            const int di = tap >> 1, dj = tap & 1;
            {
                const int ii = ia + di, jj = ja + dj;
                const bool v = (ii < 21) && (jj < 21);
                const int q = ii * 21 + jj;
                pa[tap] = (v && mask[bA * 441 + q] != 0)
                        ? (const float4*)(x + ((size_t)bA * 441 + q) * 200)
                        : (const float4*)zp;
            }
            {
                const int ii = ib + di, jj = jb + dj;
                const bool v = (ii < 21) && (jj < 21);
                const int q = ii * 21 + jj;
                pb[tap] = (v && mask[bB * 441 + q] != 0)
                        ? (const float4*)(x + ((size_t)bB * 441 + q) * 200)
                        : (const float4*)zp;
            }
        }

        float accA[16], accB[16];
        #pragma unroll
        for (int c = 0; c < 16; ++c) { accA[c] = 0.0f; accB[c] = 0.0f; }

        float4 cur[8];
        #pragma unroll
        for (int tap = 0; tap < 4; ++tap) { cur[tap] = pa[tap][0]; cur[4 + tap] = pb[tap][0]; }

        for (int k4 = 0; k4 < 50; ++k4) {
            float4 nxt[8];
            const int kn = (k4 < 49) ? (k4 + 1) : 49;
            #pragma unroll
            for (int tap = 0; tap < 4; ++tap) {
                nxt[tap]     = pa[tap][kn];
                nxt[4 + tap] = pb[tap][kn];
            }

            #pragma unroll
            for (int tap = 0; tap < 4; ++tap) {
                const float4 xa = cur[tap];
                const float4 xb = cur[4 + tap];
                const float4* wt = (const float4*)(w1s + tap * 3200 + k4 * 64);
                #pragma unroll
                for (int q = 0; q < 4; ++q) {
                    const float xsa = (q == 0) ? xa.x : (q == 1) ? xa.y : (q == 2) ? xa.z : xa.w;
                    const float xsb = (q == 0) ? xb.x : (q == 1) ? xb.y : (q == 2) ? xb.z : xb.w;
                    const float4 w0 = wt[q * 4 + 0];
                    const float4 w1v = wt[q * 4 + 1];
                    const float4 w2v = wt[q * 4 + 2];
                    const float4 w3v = wt[q * 4 + 3];
                    accA[0]  = fmaf(xsa, w0.x,  accA[0]);  accB[0]  = fmaf(xsb, w0.x,  accB[0]);
                    accA[1]  = fmaf(xsa, w0.y,  accA[1]);  accB[1]  = fmaf(xsb, w0.y,  accB[1]);
                    accA[2]  = fmaf(xsa, w0.z,  accA[2]);  accB[2]  = fmaf(xsb, w0.z,  accB[2]);
                    accA[3]  = fmaf(xsa, w0.w,  accA[3]);  accB[3]  = fmaf(xsb, w0.w,  accB[3]);
                    accA[4]  = fmaf(xsa, w1v.x, accA[4]);  accB[4]  = fmaf(xsb, w1v.x, accB[4]);
                    accA[5]  = fmaf(xsa, w1v.y, accA[5]);  accB[5]  = fmaf(xsb, w1v.y, accB[5]);
                    accA[6]  = fmaf(xsa, w1v.z, accA[6]);  accB[6]  = fmaf(xsb, w1v.z, accB[6]);
                    accA[7]  = fmaf(xsa, w1v.w, accA[7]);  accB[7]  = fmaf(xsb, w1v.w, accB[7]);
                    accA[8]  = fmaf(xsa, w2v.x, accA[8]);  accB[8]  = fmaf(xsb, w2v.x, accB[8]);
                    accA[9]  = fmaf(xsa, w2v.y, accA[9]);  accB[9]  = fmaf(xsb, w2v.y, accB[9]);
                    accA[10] = fmaf(xsa, w2v.z, accA[10]); accB[10] = fmaf(xsb, w2v.z, accB[10]);
                    accA[11] = fmaf(xsa, w2v.w, accA[11]); accB[11] = fmaf(xsb, w2v.w, accB[11]);
                    accA[12] = fmaf(xsa, w3v.x, accA[12]); accB[12] = fmaf(xsb, w3v.x, accB[12]);
                    accA[13] = fmaf(xsa, w3v.y, accA[13]); accB[13] = fmaf(xsb, w3v.y, accB[13]);
                    accA[14] = fmaf(xsa, w3v.z, accA[14]); accB[14] = fmaf(xsb, w3v.z, accB[14]);
                    accA[15] = fmaf(xsa, w3v.w, accA[15]); accB[15] = fmaf(xsb, w3v.w, accB[15]);
                }
            }
            #pragma unroll
            for (int u = 0; u < 8; ++u) cur[u] = nxt[u];
        }

        {
            const int cellA = (ia / 3) * 7 + (ja / 3);
            int* d = h2ord + ((size_t)bA * 49 + cellA) * 16;
            #pragma unroll
            for (int c = 0; c < 16; ++c) atomicMax(&d[c], f2o(accA[c]));
        }
        {
            const int cellB = (ib / 3) * 7 + (jb / 3);
            int* d = h2ord + ((size_t)bB * 49 + cellB) * 16;
            #pragma unroll
            for (int c = 0; c < 16; ++c) atomicMax(&d[c], f2o(accB[c]));
        }
    }
}

// ---------------- K2: conv2 + mask + final pool + linear + softmax ----------------
__global__ __launch_bounds__(256) void tail_kernel(
    const int*   __restrict__ h2ord, // [1024,49,16] ordered-int pooled conv1
    const float* __restrict__ m2,    // [1024,49]
    const float* __restrict__ W2,    // [5,5,16,32]
    const float* __restrict__ Wlin,  // [32,2]
    const float* __restrict__ blin,  // [2]
    float* __restrict__ out)         // [1024,2]
{
    __shared__ float h2s[49][16];
    __shared__ float m2s[49];
    __shared__ float hc[9][32];
    __shared__ float m3s[9];
    __shared__ float h4[32];

    const int b = blockIdx.x;
    const int t = threadIdx.x;

    if (t < 49) m2s[t] = m2[b * 49 + t];
    __syncthreads();

    for (int v = t; v < 784; v += 256) {
        const int cell = v >> 4;
        const int o = h2ord[b * 784 + v];
        h2s[cell][v & 15] = (m2s[cell] > 0.0f) ? o2f(o) : 0.0f;
    }
    __syncthreads();

    // conv2: 7x7 -> 3x3, 16 -> 32 channels; gate by 5x5 mask-pool
    for (int t2 = t; t2 < 288; t2 += 256) {
        const int cell = t2 >> 5;
        const int oc   = t2 & 31;
        const int ci = cell / 3, cj = cell - ci * 3;
        float acc = 0.0f;
        float mm = 0.0f;
        #pragma unroll
        for (int di = 0; di < 5; ++di) {
            #pragma unroll
            for (int dj = 0; dj < 5; ++dj) {
                const int s = (ci + di) * 7 + (cj + dj);
                mm = fmaxf(mm, m2s[s]);
                const float* __restrict__ wrow = W2 + ((di * 5 + dj) * 16) * 32 + oc;
                #pragma unroll
                for (int c = 0; c < 16; ++c)
                    acc = fmaf(h2s[s][c], wrow[c * 32], acc);
            }
        }
        hc[cell][oc] = (mm > 0.0f) ? acc : 0.0f;
        if (oc == 0) m3s[cell] = mm;
    }
    __syncthreads();

    // final masked maxpool 3x3/1 on 3x3 -> 1x1
    if (t < 32) {
        float best = NEGINF;
        bool any = false;
        #pragma unroll
        for (int cell = 0; cell < 9; ++cell) {
            if (m3s[cell] > 0.0f) { any = true; best = fmaxf(best, hc[cell][t]); }
        }
        h4[t] = any ? best : 0.0f;
    }
    __syncthreads();

    if (t == 0) {
        float l0 = blin[0], l1 = blin[1];
        #pragma unroll
        for (int c = 0; c < 32; ++c) {
            l0 = fmaf(h4[c], Wlin[c * 2 + 0], l0);
            l1 = fmaf(h4[c], Wlin[c * 2 + 1], l1);
        }
        const float mx = fmaxf(l0, l1);
        const float e0 = expf(l0 - mx);
        const float e1 = expf(l1 - mx);
        const float inv = 1.0f / (e0 + e1);
        out[b * 2 + 0] = e0 * inv;
        out[b * 2 + 1] = e1 * inv;
    }
}

extern "C" void kernel_launch(void* const* d_in, const int* in_sizes, int n_in,
                              void* d_out, int out_size, void* d_ws, size_t ws_size,
                              hipStream_t stream) {
    const float* x    = (const float*)d_in[0];
    const int*   mask = (const int*)d_in[1];
    const float* W1   = (const float*)d_in[2];
    const float* W2   = (const float*)d_in[3];
    const float* Wlin = (const float*)d_in[4];
    const float* blin = (const float*)d_in[5];
    float* out = (float*)d_out;

    int*   h2ord = (int*)d_ws;                   // 1024*49*16 ints
    float* m2    = (float*)(h2ord + 1024 * 49 * 16);
    int*   wl    = (int*)(m2 + 1024 * 49);       // 451584 ints
    int*   nact  = wl + 1024 * 441;
    float* zp    = (float*)(nact + 4);           // 256 floats

    hipMemsetAsync(nact, 0, sizeof(int), stream);
    hipMemsetAsync(zp, 0, 256 * sizeof(float), stream);
    compact_kernel<<<1024, 256, 0, stream>>>(mask, wl, nact, h2ord, m2);
    conv1_kernel<<<512, 256, 0, stream>>>(x, mask, W1, wl, nact, zp, h2ord);
    tail_kernel<<<1024, 256, 0, stream>>>(h2ord, m2, W2, Wlin, blin, out);
}

// Round 6
// 807.139 us; speedup vs baseline: 1.0193x; 1.0193x over previous
//
#include <hip/hip_runtime.h>
#include <math.h>

// SparseNet: conv1(2x2,200->16,pad(0,1)) * mask -> maskedpool 3x3/3 ->
// conv2(5x5,16->32,VALID) * pooledmask -> maskedpool 3x3/1 -> linear(32,2) -> softmax
// B=1024, H=W=21, Cin=200.
//
// ws layout:
//   h2ord [1024*49*16] int  (3.2 MB)  pooled conv1 output (ordered-int encoding)
//   m2    [1024*49] float             pooled mask

#define NEGINF -1e30f

// Order-preserving float<->int map so masked max-pool can run as atomicMax.
__device__ __forceinline__ int f2o(float f) {
    int i = __float_as_int(f);
    return (i >= 0) ? i : (i ^ 0x7FFFFFFF);
}
__device__ __forceinline__ float o2f(int o) {
    return __int_as_float((o >= 0) ? o : (o ^ 0x7FFFFFFF));
}

// ---------------- K1: conv1 + fused masked pool, one batch per block ----------------
// 128 threads (2 waves), S=2 sites/thread via in-LDS compacted worklist.
// Weight loads: wave-uniform global addresses in uniform control flow -> scalar
// (s_load) pipe, no LDS staging, no VMEM broadcast pressure.
// Inactive taps: pointer redirected to the site's own (cached) row, value
// multiplied by 0.0 -> branch-free, exact +0.0 contribution.
// Pool: LDS atomicMax on ordered ints (exact), no global atomics.
__global__ __launch_bounds__(128, 4) void conv1_pool_kernel(
    const float* __restrict__ x,     // [1024,21,21,200]
    const int*   __restrict__ mask,  // [1024,21,21]
    const float* __restrict__ W1,    // [2,2,200,16] laid out [tap][k][oc]
    int*   __restrict__ h2ord,       // [1024,49,16]
    float* __restrict__ m2)          // [1024,49]
{
    __shared__ int h2p[49 * 16];             // pooled accumulators (ordered-int)
    __shared__ unsigned short act[441];      // compacted active-site list
    __shared__ unsigned char msk[441];
    __shared__ int cnt;

    const int b = blockIdx.x;
    const int t = threadIdx.x;

    if (t == 0) cnt = 0;
    for (int v = t; v < 784; v += 128) h2p[v] = 0x80000000;  // INT_MIN
    __syncthreads();

    for (int p = t; p < 441; p += 128) {
        const int mv = mask[b * 441 + p];
        msk[p] = (unsigned char)(mv != 0);
        if (mv != 0) act[atomicAdd(&cnt, 1)] = (unsigned short)p;
    }
    __syncthreads();

    const int na = cnt;
    const float* __restrict__ xb = x + (size_t)b * 441 * 200;

    // uniform trip count; lanes past the end recompute the last site (benign for max)
    const int npairs = (na + 1) >> 1;
    for (int base = 0; base < npairs; base += 128) {
        const int pi = min(base + t, npairs - 1);
        const int pA = act[min(2 * pi, na - 1)];
        const int pB = act[min(2 * pi + 1, na - 1)];
        const int ia = pA / 21, ja = pA - ia * 21;
        const int ib = pB / 21, jb = pB - ib * 21;

        const float4* pa[4];
        const float4* pb[4];
        float ga[4], gb[4];
        #pragma unroll
        for (int tap = 0; tap < 4; ++tap) {
            const int di = tap >> 1, dj = tap & 1;
            {
                const int ii = ia + di, jj = ja + dj;
                const bool v = (ii < 21) && (jj < 21);
                const int q = v ? (ii * 21 + jj) : pA;
                const bool on = v && msk[q];
                ga[tap] = on ? 1.0f : 0.0f;
                pa[tap] = (const float4*)(xb + (size_t)(on ? q : pA) * 200);
            }
            {
                const int ii = ib + di, jj = jb + dj;
                const bool v = (ii < 21) && (jj < 21);
                const int q = v ? (ii * 21 + jj) : pB;
                const bool on = v && msk[q];
                gb[tap] = on ? 1.0f : 0.0f;
                pb[tap] = (const float4*)(xb + (size_t)(on ? q : pB) * 200);
            }
        }

        float accA[16], accB[16];
        #pragma unroll
        for (int c = 0; c < 16; ++c) { accA[c] = 0.0f; accB[c] = 0.0f; }

        #pragma unroll 2
        for (int k4 = 0; k4 < 50; ++k4) {
            #pragma unroll
            for (int tap = 0; tap < 4; ++tap) {
                float4 xa = pa[tap][k4];
                float4 xb4 = pb[tap][k4];
                const float mA = ga[tap], mB = gb[tap];
                xa.x *= mA; xa.y *= mA; xa.z *= mA; xa.w *= mA;
                xb4.x *= mB; xb4.y *= mB; xb4.z *= mB; xb4.w *= mB;
                // wave-uniform address, uniform CF -> scalar load expected
                const float4* __restrict__ wt = (const float4*)(W1 + tap * 3200 + k4 * 64);
                #pragma unroll
                for (int q = 0; q < 4; ++q) {
                    const float xsa = (q == 0) ? xa.x : (q == 1) ? xa.y : (q == 2) ? xa.z : xa.w;
                    const float xsb = (q == 0) ? xb4.x : (q == 1) ? xb4.y : (q == 2) ? xb4.z : xb4.w;
                    const float4 w0 = wt[q * 4 + 0];
                    const float4 w1v = wt[q * 4 + 1];
                    const float4 w2v = wt[q * 4 + 2];
                    const float4 w3v = wt[q * 4 + 3];
                    accA[0]  = fmaf(xsa, w0.x,  accA[0]);  accB[0]  = fmaf(xsb, w0.x,  accB[0]);
                    accA[1]  = fmaf(xsa, w0.y,  accA[1]);  accB[1]  = fmaf(xsb, w0.y,  accB[1]);
                    accA[2]  = fmaf(xsa, w0.z,  accA[2]);  accB[2]  = fmaf(xsb, w0.z,  accB[2]);
                    accA[3]  = fmaf(xsa, w0.w,  accA[3]);  accB[3]  = fmaf(xsb, w0.w,  accB[3]);
                    accA[4]  = fmaf(xsa, w1v.x, accA[4]);  accB[4]  = fmaf(xsb, w1v.x, accB[4]);
                    accA[5]  = fmaf(xsa, w1v.y, accA[5]);  accB[5]  = fmaf(xsb, w1v.y, accB[5]);
                    accA[6]  = fmaf(xsa, w1v.z, accA[6]);  accB[6]  = fmaf(xsb, w1v.z, accB[6]);
                    accA[7]  = fmaf(xsa, w1v.w, accA[7]);  accB[7]  = fmaf(xsb, w1v.w, accB[7]);
                    accA[8]  = fmaf(xsa, w2v.x, accA[8]);  accB[8]  = fmaf(xsb, w2v.x, accB[8]);
                    accA[9]  = fmaf(xsa, w2v.y, accA[9]);  accB[9]  = fmaf(xsb, w2v.y, accB[9]);
                    accA[10] = fmaf(xsa, w2v.z, accA[10]); accB[10] = fmaf(xsb, w2v.z, accB[10]);
                    accA[11] = fmaf(xsa, w2v.w, accA[11]); accB[11] = fmaf(xsb, w2v.w, accB[11]);
                    accA[12] = fmaf(xsa, w3v.x, accA[12]); accB[12] = fmaf(xsb, w3v.x, accB[12]);
                    accA[13] = fmaf(xsa, w3v.y, accA[13]); accB[13] = fmaf(xsb, w3v.y, accB[13]);
                    accA[14] = fmaf(xsa, w3v.z, accA[14]); accB[14] = fmaf(xsb, w3v.z, accB[14]);
                    accA[15] = fmaf(xsa, w3v.w, accA[15]); accB[15] = fmaf(xsb, w3v.w, accB[15]);
                }
            }
        }

        {
            const int cA = (ia / 3) * 7 + (ja / 3);
            #pragma unroll
            for (int c = 0; c < 16; ++c) atomicMax(&h2p[cA * 16 + c], f2o(accA[c]));
        }
        {
            const int cB = (ib / 3) * 7 + (jb / 3);
            #pragma unroll
            for (int c = 0; c < 16; ++c) atomicMax(&h2p[cB * 16 + c], f2o(accB[c]));
        }
    }
    __syncthreads();

    for (int v = t; v < 784; v += 128) h2ord[(size_t)b * 784 + v] = h2p[v];
    if (t < 49) {
        const int pr = t / 7, pc = t - pr * 7;
        int any = 0;
        #pragma unroll
        for (int r = 0; r < 3; ++r) {
            const unsigned char* mr = &msk[(pr * 3 + r) * 21 + pc * 3];
            any |= mr[0] | mr[1] | mr[2];
        }
        m2[b * 49 + t] = any ? 1.0f : 0.0f;
    }
}

// ---------------- K2: conv2 + mask + final pool + linear + softmax ----------------
__global__ __launch_bounds__(256) void tail_kernel(
    const int*   __restrict__ h2ord, // [1024,49,16] ordered-int pooled conv1
    const float* __restrict__ m2,    // [1024,49]
    const float* __restrict__ W2,    // [5,5,16,32]
    const float* __restrict__ Wlin,  // [32,2]
    const float* __restrict__ blin,  // [2]
    float* __restrict__ out)         // [1024,2]
{
    __shared__ float h2s[49][16];
    __shared__ float m2s[49];
    __shared__ float hc[9][32];
    __shared__ float m3s[9];
    __shared__ float h4[32];

    const int b = blockIdx.x;
    const int t = threadIdx.x;

    if (t < 49) m2s[t] = m2[b * 49 + t];
    __syncthreads();

    for (int v = t; v < 784; v += 256) {
        const int cell = v >> 4;
        const int o = h2ord[(size_t)b * 784 + v];
        h2s[cell][v & 15] = (m2s[cell] > 0.0f) ? o2f(o) : 0.0f;
    }
    __syncthreads();

    for (int t2 = t; t2 < 288; t2 += 256) {
        const int cell = t2 >> 5;
        const int oc   = t2 & 31;
        const int ci = cell / 3, cj = cell - ci * 3;
        float acc = 0.0f;
        float mm = 0.0f;
        #pragma unroll
        for (int di = 0; di < 5; ++di) {
            #pragma unroll
            for (int dj = 0; dj < 5; ++dj) {
                const int s = (ci + di) * 7 + (cj + dj);
                mm = fmaxf(mm, m2s[s]);
                const float* __restrict__ wrow = W2 + ((di * 5 + dj) * 16) * 32 + oc;
                #pragma unroll
                for (int c = 0; c < 16; ++c)
                    acc = fmaf(h2s[s][c], wrow[c * 32], acc);
            }
        }
        hc[cell][oc] = (mm > 0.0f) ? acc : 0.0f;
        if (oc == 0) m3s[cell] = mm;
    }
    __syncthreads();

    if (t < 32) {
        float best = NEGINF;
        bool any = false;
        #pragma unroll
        for (int cell = 0; cell < 9; ++cell) {
            if (m3s[cell] > 0.0f) { any = true; best = fmaxf(best, hc[cell][t]); }
        }
        h4[t] = any ? best : 0.0f;
    }
    __syncthreads();

    if (t == 0) {
        float l0 = blin[0], l1 = blin[1];
        #pragma unroll
        for (int c = 0; c < 32; ++c) {
            l0 = fmaf(h4[c], Wlin[c * 2 + 0], l0);
            l1 = fmaf(h4[c], Wlin[c * 2 + 1], l1);
        }
        const float mx = fmaxf(l0, l1);
        const float e0 = expf(l0 - mx);
        const float e1 = expf(l1 - mx);
        const float inv = 1.0f / (e0 + e1);
        out[b * 2 + 0] = e0 * inv;
        out[b * 2 + 1] = e1 * inv;
    }
}

extern "C" void kernel_launch(void* const* d_in, const int* in_sizes, int n_in,
                              void* d_out, int out_size, void* d_ws, size_t ws_size,
                              hipStream_t stream) {
    const float* x    = (const float*)d_in[0];
    const int*   mask = (const int*)d_in[1];
    const float* W1   = (const float*)d_in[2];
    const float* W2   = (const float*)d_in[3];
    const float* Wlin = (const float*)d_in[4];
    const float* blin = (const float*)d_in[5];
    float* out = (float*)d_out;

    int*   h2ord = (int*)d_ws;                       // 1024*49*16 ints
    float* m2    = (float*)(h2ord + 1024 * 49 * 16); // 1024*49 floats

    conv1_pool_kernel<<<1024, 128, 0, stream>>>(x, mask, W1, h2ord, m2);
    tail_kernel<<<1024, 256, 0, stream>>>(h2ord, m2, W2, Wlin, blin, out);
}

// Round 7
// 675.999 us; speedup vs baseline: 1.2170x; 1.1940x over previous
//
#include <hip/hip_runtime.h>
#include <math.h>

// SparseNet: conv1(2x2,200->16,pad(0,1)) * mask -> maskedpool 3x3/3 ->
// conv2(5x5,16->32,VALID) * pooledmask -> maskedpool 3x3/1 -> linear(32,2) -> softmax
// B=1024, H=W=21, Cin=200.
//
// ws layout:
//   h2ord [1024*49*16] int  (3.2 MB)  pooled conv1 output (ordered-int encoding)
//   m2    [1024*49] float             pooled mask

#define NEGINF -1e30f

// Order-preserving float<->int map so masked max-pool can run as atomicMax.
__device__ __forceinline__ int f2o(float f) {
    int i = __float_as_int(f);
    return (i >= 0) ? i : (i ^ 0x7FFFFFFF);
}
__device__ __forceinline__ float o2f(int o) {
    return __int_as_float((o >= 0) ? o : (o ^ 0x7FFFFFFF));
}

// ---------------- K1: conv1 + fused masked pool, one batch per block ----------------
// 256 threads (4 waves), 1 site/thread -> grid 1024 = 4 blocks/CU = 16 waves/CU.
// Site list built with ORDER-PRESERVING ballot-scan compaction so adjacent lanes
// work on adjacent pixels (tap rows overlap -> L1 line reuse).
// Explicit 2-deep software prefetch pipeline on the 4 tap streams (~12 loads in
// flight per lane). Weights: wave-uniform scalar loads. Pool: LDS atomicMax.
__global__ __launch_bounds__(256, 4) void conv1_pool_kernel(
    const float* __restrict__ x,     // [1024,21,21,200]
    const int*   __restrict__ mask,  // [1024,21,21]
    const float* __restrict__ W1,    // [2,2,200,16] laid out [tap][k][oc]
    int*   __restrict__ h2ord,       // [1024,49,16]
    float* __restrict__ m2)          // [1024,49]
{
    __shared__ int h2p[49 * 16];             // pooled accumulators (ordered-int)
    __shared__ unsigned short act[441];      // compacted, ORDERED active-site list
    __shared__ unsigned char msk[441];
    __shared__ int woff[4];
    __shared__ int carry;

    const int b = blockIdx.x;
    const int t = threadIdx.x;
    const int wid = t >> 6, lane = t & 63;

    if (t == 0) carry = 0;
    for (int v = t; v < 784; v += 256) h2p[v] = 0x80000000;  // INT_MIN
    for (int p = t; p < 441; p += 256)
        msk[p] = (unsigned char)(mask[b * 441 + p] != 0);
    __syncthreads();

    // ---- order-preserving compaction: two passes of 256 ----
    for (int pass = 0; pass < 2; ++pass) {
        const int p = pass * 256 + t;
        const bool on = (p < 441) && msk[p];
        const unsigned long long bal = __ballot(on);
        if (lane == 0) woff[wid] = __popcll(bal);
        __syncthreads();
        int wbase = carry;
        for (int i = 0; i < wid; ++i) wbase += woff[i];
        if (on) act[wbase + __popcll(bal & ((1ull << lane) - 1ull))] = (unsigned short)p;
        __syncthreads();
        if (t == 0) carry += woff[0] + woff[1] + woff[2] + woff[3];
        __syncthreads();
    }
    const int na = carry;

    const float* __restrict__ xb = x + (size_t)b * 441 * 200;

    if (na > 0) {
        for (int base = 0; base < na; base += 256) {
            // lanes past the end recompute the last site (benign for max pool)
            const int p = act[min(base + t, na - 1)];
            const int i = p / 21, j = p - i * 21;

            const float4* pp[4];
            float g[4];
            #pragma unroll
            for (int tap = 0; tap < 4; ++tap) {
                const int ii = i + (tap >> 1), jj = j + (tap & 1);
                const bool v = (ii < 21) && (jj < 21);
                const int q = v ? (ii * 21 + jj) : p;
                const bool on = v && msk[q];
                g[tap] = on ? 1.0f : 0.0f;
                pp[tap] = (const float4*)(xb + (size_t)(on ? q : p) * 200);
            }

            float acc[16];
            #pragma unroll
            for (int c = 0; c < 16; ++c) acc[c] = 0.0f;

            // 2-deep software pipeline over k4 = 0..49
            float4 bufA[4], bufB[4];
            #pragma unroll
            for (int tap = 0; tap < 4; ++tap) { bufA[tap] = pp[tap][0]; bufB[tap] = pp[tap][1]; }

            for (int k4 = 0; k4 < 50; ++k4) {
                float4 nxt[4];
                const int kn = (k4 + 2 < 50) ? (k4 + 2) : 49;
                #pragma unroll
                for (int tap = 0; tap < 4; ++tap) nxt[tap] = pp[tap][kn];

                #pragma unroll
                for (int tap = 0; tap < 4; ++tap) {
                    float4 xa = bufA[tap];
                    const float mA = g[tap];
                    xa.x *= mA; xa.y *= mA; xa.z *= mA; xa.w *= mA;
                    // wave-uniform address, uniform CF -> scalar load expected
                    const float4* __restrict__ wt = (const float4*)(W1 + tap * 3200 + k4 * 64);
                    #pragma unroll
                    for (int q = 0; q < 4; ++q) {
                        const float xs = (q == 0) ? xa.x : (q == 1) ? xa.y : (q == 2) ? xa.z : xa.w;
                        const float4 w0 = wt[q * 4 + 0];
                        const float4 w1v = wt[q * 4 + 1];
                        const float4 w2v = wt[q * 4 + 2];
                        const float4 w3v = wt[q * 4 + 3];
                        acc[0]  = fmaf(xs, w0.x,  acc[0]);
                        acc[1]  = fmaf(xs, w0.y,  acc[1]);
                        acc[2]  = fmaf(xs, w0.z,  acc[2]);
                        acc[3]  = fmaf(xs, w0.w,  acc[3]);
                        acc[4]  = fmaf(xs, w1v.x, acc[4]);
                        acc[5]  = fmaf(xs, w1v.y, acc[5]);
                        acc[6]  = fmaf(xs, w1v.z, acc[6]);
                        acc[7]  = fmaf(xs, w1v.w, acc[7]);
                        acc[8]  = fmaf(xs, w2v.x, acc[8]);
                        acc[9]  = fmaf(xs, w2v.y, acc[9]);
                        acc[10] = fmaf(xs, w2v.z, acc[10]);
                        acc[11] = fmaf(xs, w2v.w, acc[11]);
                        acc[12] = fmaf(xs, w3v.x, acc[12]);
                        acc[13] = fmaf(xs, w3v.y, acc[13]);
                        acc[14] = fmaf(xs, w3v.z, acc[14]);
                        acc[15] = fmaf(xs, w3v.w, acc[15]);
                    }
                }
                #pragma unroll
                for (int tap = 0; tap < 4; ++tap) { bufA[tap] = bufB[tap]; bufB[tap] = nxt[tap]; }
            }

            const int cell = (i / 3) * 7 + (j / 3);
            #pragma unroll
            for (int c = 0; c < 16; ++c) atomicMax(&h2p[cell * 16 + c], f2o(acc[c]));
        }
    }
    __syncthreads();

    for (int v = t; v < 784; v += 256) h2ord[(size_t)b * 784 + v] = h2p[v];
    if (t < 49) {
        const int pr = t / 7, pc = t - pr * 7;
        int any = 0;
        #pragma unroll
        for (int r = 0; r < 3; ++r) {
            const unsigned char* mr = &msk[(pr * 3 + r) * 21 + pc * 3];
            any |= mr[0] | mr[1] | mr[2];
        }
        m2[b * 49 + t] = any ? 1.0f : 0.0f;
    }
}

// ---------------- K2: conv2 + mask + final pool + linear + softmax ----------------
__global__ __launch_bounds__(256) void tail_kernel(
    const int*   __restrict__ h2ord, // [1024,49,16] ordered-int pooled conv1
    const float* __restrict__ m2,    // [1024,49]
    const float* __restrict__ W2,    // [5,5,16,32]
    const float* __restrict__ Wlin,  // [32,2]
    const float* __restrict__ blin,  // [2]
    float* __restrict__ out)         // [1024,2]
{
    __shared__ float h2s[49][16];
    __shared__ float m2s[49];
    __shared__ float hc[9][32];
    __shared__ float m3s[9];
    __shared__ float h4[32];

    const int b = blockIdx.x;
    const int t = threadIdx.x;

    if (t < 49) m2s[t] = m2[b * 49 + t];
    __syncthreads();

    for (int v = t; v < 784; v += 256) {
        const int cell = v >> 4;
        const int o = h2ord[(size_t)b * 784 + v];
        h2s[cell][v & 15] = (m2s[cell] > 0.0f) ? o2f(o) : 0.0f;
    }
    __syncthreads();

    for (int t2 = t; t2 < 288; t2 += 256) {
        const int cell = t2 >> 5;
        const int oc   = t2 & 31;
        const int ci = cell / 3, cj = cell - ci * 3;
        float acc = 0.0f;
        float mm = 0.0f;
        #pragma unroll
        for (int di = 0; di < 5; ++di) {
            #pragma unroll
            for (int dj = 0; dj < 5; ++dj) {
                const int s = (ci + di) * 7 + (cj + dj);
                mm = fmaxf(mm, m2s[s]);
                const float* __restrict__ wrow = W2 + ((di * 5 + dj) * 16) * 32 + oc;
                #pragma unroll
                for (int c = 0; c < 16; ++c)
                    acc = fmaf(h2s[s][c], wrow[c * 32], acc);
            }
        }
        hc[cell][oc] = (mm > 0.0f) ? acc : 0.0f;
        if (oc == 0) m3s[cell] = mm;
    }
    __syncthreads();

    if (t < 32) {
        float best = NEGINF;
        bool any = false;
        #pragma unroll
        for (int cell = 0; cell < 9; ++cell) {
            if (m3s[cell] > 0.0f) { any = true; best = fmaxf(best, hc[cell][t]); }
        }
        h4[t] = any ? best : 0.0f;
    }
    __syncthreads();

    if (t == 0) {
        float l0 = blin[0], l1 = blin[1];
        #pragma unroll
        for (int c = 0; c < 32; ++c) {
            l0 = fmaf(h4[c], Wlin[c * 2 + 0], l0);
            l1 = fmaf(h4[c], Wlin[c * 2 + 1], l1);
        }
        const float mx = fmaxf(l0, l1);
        const float e0 = expf(l0 - mx);
        const float e1 = expf(l1 - mx);
        const float inv = 1.0f / (e0 + e1);
        out[b * 2 + 0] = e0 * inv;
        out[b * 2 + 1] = e1 * inv;
    }
}

extern "C" void kernel_launch(void* const* d_in, const int* in_sizes, int n_in,
                              void* d_out, int out_size, void* d_ws, size_t ws_size,
                              hipStream_t stream) {
    const float* x    = (const float*)d_in[0];
    const int*   mask = (const int*)d_in[1];
    const float* W1   = (const float*)d_in[2];
    const float* W2   = (const float*)d_in[3];
    const float* Wlin = (const float*)d_in[4];
    const float* blin = (const float*)d_in[5];
    float* out = (float*)d_out;

    int*   h2ord = (int*)d_ws;                       // 1024*49*16 ints
    float* m2    = (float*)(h2ord + 1024 * 49 * 16); // 1024*49 floats

    conv1_pool_kernel<<<1024, 256, 0, stream>>>(x, mask, W1, h2ord, m2);
    tail_kernel<<<1024, 256, 0, stream>>>(h2ord, m2, W2, Wlin, blin, out);
}